// Round 1
// baseline (351.519 us; speedup 1.0000x reference)
//
#include <hip/hip_runtime.h>
#include <math.h>

// Problem constants
#define NP 8836          // number of patches per image (94*94)
#define PW 94            // patches per row
#define IW 96            // image width/height
#define CH 256           // channels
#define NT2 35           // ceil(8836/256) output tiles per dim
#define KT2 18           // K steps: 2304/128 (BK=128 fp8 bytes)

typedef int   i32x4  __attribute__((ext_vector_type(4)));
typedef int   i32x8  __attribute__((ext_vector_type(8)));
typedef float f32x16 __attribute__((ext_vector_type(16)));

__device__ __forceinline__ unsigned int ordf(float f) {
  unsigned int u = __float_as_uint(f);
  return (u & 0x80000000u) ? ~u : (u | 0x80000000u);
}

typedef const __attribute__((address_space(1))) void GvoidC;
typedef __attribute__((address_space(3))) void Lvoid;
__device__ __forceinline__ void gl16(const void* g, void* l) {
  __builtin_amdgcn_global_load_lds((GvoidC*)g, (Lvoid*)l, 16, 0, 0);
}

// ---------------------------------------------------------------------------
// 1) Convert+transpose [C, 9216] fp32 -> [9216, C] fp8 (HW v_cvt encoding).
// ---------------------------------------------------------------------------
__global__ __launch_bounds__(256) void prep_kernel(
    const float* __restrict__ inA, const float* __restrict__ inB,
    unsigned int* __restrict__ TA, unsigned int* __restrict__ TB) {
  __shared__ float tile[64][65];
  int bid = blockIdx.x;            // [0, 1152)
  const float* src; unsigned int* dst;
  if (bid < 576) { src = inA; dst = TA; }
  else           { src = inB; dst = TB; bid -= 576; }
  int cT  = bid & 3;        // c-tile   [0,4)  (64 channels)
  int xyT = bid >> 2;       // xy-tile  [0,144)
  int t = threadIdx.x;
  int l = t & 63, h = t >> 6;

  #pragma unroll
  for (int i = 0; i < 16; ++i) {
    int c = h * 16 + i;
    tile[c][l] = src[(size_t)(cT * 64 + c) * (IW * IW) + xyT * 64 + l];
  }
  __syncthreads();
  int cu = t & 15;          // u32 column within the 64-channel tile
  #pragma unroll
  for (int i = 0; i < 4; ++i) {
    int xy = (t >> 4) + i * 16;
    int c = cu * 4;
    unsigned int v = __builtin_amdgcn_cvt_pk_fp8_f32(tile[c][xy],     tile[c + 1][xy], 0, false);
    v              = __builtin_amdgcn_cvt_pk_fp8_f32(tile[c + 2][xy], tile[c + 3][xy], v, true);
    dst[(size_t)(xyT * 64 + xy) * 64 + cT * 16 + cu] = v;
  }
}

// ---------------------------------------------------------------------------
// 2) Per-patch squared norms from the fp8 images (consistent with GEMM dtype).
// ---------------------------------------------------------------------------
__global__ void norms_kernel(const unsigned int* __restrict__ TA, const unsigned int* __restrict__ TB,
                             float* __restrict__ rnormS, float* __restrict__ normS,
                             float* __restrict__ normsqS, float* __restrict__ synsq) {
  int wid  = blockIdx.x * 4 + (threadIdx.x >> 6);
  int lane = threadIdx.x & 63;
  bool isStyle = wid < NP;
  int p = isStyle ? wid : wid - NP;
  if (p >= NP) return;
  const unsigned int* T = isStyle ? TB : TA;
  int pi = p / PW, pj = p % PW;
  float s = 0.f;
  #pragma unroll
  for (int kh = 0; kh < 3; ++kh) {
    #pragma unroll
    for (int kw = 0; kw < 3; ++kw) {
      unsigned int v = T[(size_t)((pi + kh) * IW + (pj + kw)) * 64 + lane];
      float f0 = __builtin_amdgcn_cvt_f32_fp8(v, 0);
      float f1 = __builtin_amdgcn_cvt_f32_fp8(v, 1);
      float f2 = __builtin_amdgcn_cvt_f32_fp8(v, 2);
      float f3 = __builtin_amdgcn_cvt_f32_fp8(v, 3);
      s += f0 * f0 + f1 * f1 + f2 * f2 + f3 * f3;
    }
  }
  #pragma unroll
  for (int m = 32; m >= 1; m >>= 1) s += __shfl_xor(s, m, 64);
  if (lane == 0) {
    if (isStyle) {
      normsqS[p] = s;
      float n = sqrtf(s);
      normS[p]  = n;
      rnormS[p] = 1.f / n;
    } else {
      synsq[p] = s;
    }
  }
}

// ---------------------------------------------------------------------------
// 3) MX-fp8 implicit-im2col GEMM+argmax, 256x256 tile, 8 waves (2Mx4N),
//    BK=128 bytes, double-buffered 128 KiB LDS, phased K-loop:
//    per K-step: issue 8 global_load_lds for tile kt+1 -> other buffer,
//    s_waitcnt vmcnt(8) (counted, never 0 in steady state), raw s_barrier,
//    then 4 phases of {ds_read frags; barrier; setprio(1); 4 mfma; setprio(0);
//    barrier}. B-frags of each k-half are reused across the two mi-pair
//    phases. Chunk-XOR LDS swizzle kept from previous version: logical 16B
//    chunk q of row r lives at slot q ^ (r&7); staging pre-swizzles the
//    GLOBAL source chunk so the LDS dest stays linear (global_load_lds
//    requirement), reads apply the same XOR.
// ---------------------------------------------------------------------------
__device__ __forceinline__ i32x8 ldfrag(const unsigned char* rowp, int o0) {
  i32x4 lo = *(const i32x4*)(rowp + o0);
  i32x4 hi = *(const i32x4*)(rowp + (o0 ^ 16));   // (c0+1)^sw = (c0^sw)^1
  return __builtin_shufflevector(lo, hi, 0, 1, 2, 3, 4, 5, 6, 7);
}

#define MFMA_SC(AF, BF, ACC) \
  __builtin_amdgcn_mfma_scale_f32_32x32x64_f8f6f4(AF, BF, ACC, \
      0, 0,              /* A fmt = fp8(e4m3), B fmt = fp8 */  \
      0, 0x7F7F7F7F,     /* opsel_a, scale_a = 1.0 */          \
      0, 0x7F7F7F7F)     /* opsel_b, scale_b = 1.0 */

#define PHASE_BAR() do { \
  asm volatile("" ::: "memory"); \
  __builtin_amdgcn_s_barrier(); \
  asm volatile("" ::: "memory"); } while (0)

__global__ __launch_bounds__(512, 2) void gemm_argmax_kernel(
    const unsigned char* __restrict__ TA, const unsigned char* __restrict__ TB,
    const float* __restrict__ rnormS, unsigned long long* __restrict__ best) {
  // [2 buffers][A 32KB | B 32KB]
  __shared__ unsigned char lds[131072];

  const int pid = blockIdx.x;
  const int mt = pid % NT2, nt = pid / NT2;
  const int q0 = mt * 256, s0 = nt * 256;
  const int t = threadIdx.x, lane = t & 63, wave = t >> 6;
  const int wm = wave >> 2, wn = wave & 3;        // 2 x 4 wave grid

  // Staging: instr i of thread t writes LDS offset i*8192 + t*16,
  // i.e. row 64*i + (t>>3), slot t&7. Fetch global chunk qc = (t&7)^(row&7).
  const int rr = t >> 3;
  const int qc = (t & 7) ^ (rr & 7);
  const unsigned char* gA[4];
  const unsigned char* gB[4];
  #pragma unroll
  for (int i = 0; i < 4; ++i) {
    int qa = q0 + 64 * i + rr; if (qa > NP - 1) qa = NP - 1;
    int sa = s0 + 64 * i + rr; if (sa > NP - 1) sa = NP - 1;
    gA[i] = TA + (size_t)((qa / PW) * IW + (qa % PW)) * CH + qc * 16;
    gB[i] = TB + (size_t)((sa / PW) * IW + (sa % PW)) * CH + qc * 16;
  }
  const int t16 = t * 16;

  f32x16 acc[4][2];
  #pragma unroll
  for (int mi = 0; mi < 4; ++mi)
    #pragma unroll
    for (int ni = 0; ni < 2; ++ni)
      #pragma unroll
      for (int j = 0; j < 16; ++j) acc[mi][ni][j] = 0.f;

  // Fragment reads: row = wm*128 + mi*32 + (lane&31) (A), wn*64 + ni*32 + ...
  // (B), stride 128 B. k-half h: logical chunks c0 = 2*(lane>>5) + 4h, c0+1;
  // slot = c ^ (lane&7) (row&7 == lane&7 for all offsets used).
  const int kq = lane >> 5, sw = lane & 7;
  const int oh0 = ((2 * kq)     ^ sw) * 16;
  const int oh1 = ((2 * kq + 4) ^ sw) * 16;
  const int aoff = (wm * 128 + (lane & 31)) * 128;
  const int boff = 32768 + (wn * 64 + (lane & 31)) * 128;

  unsigned char* cur = lds;
  unsigned char* nxt = lds + 65536;

  // Prologue: stage tile 0 (choff = 0).
  #pragma unroll
  for (int i = 0; i < 4; ++i) {
    gl16(gA[i], cur + i * 8192 + t16);
    gl16(gB[i], cur + 32768 + i * 8192 + t16);
  }

  #pragma unroll 1
  for (int kt = 0; kt < KT2; ++kt) {
    // Issue all 8 loads for tile kt+1 into the other buffer. Safe: the
    // trailing barrier of iter kt-1 guarantees all reads of `nxt` retired.
    if (kt + 1 < KT2) {
      int c = (kt + 1) >> 1;                       // which (kh,kw) of 9
      int kh = c / 3, kw = c - kh * 3;
      int choff = (kh * IW + kw) * CH + ((kt + 1) & 1) * 128;
      #pragma unroll
      for (int i = 0; i < 4; ++i) {
        gl16(gA[i] + choff, nxt + i * 8192 + t16);
        gl16(gB[i] + choff, nxt + 32768 + i * 8192 + t16);
      }
      // Tile kt's 8 loads (issued a full K-step ago) must be done; the 8
      // newest (tile kt+1) stay in flight across the barrier.
      asm volatile("s_waitcnt vmcnt(8)" ::: "memory");
    } else {
      asm volatile("s_waitcnt vmcnt(0)" ::: "memory");
    }
    __builtin_amdgcn_s_barrier();
    asm volatile("" ::: "memory");

    const unsigned char* A0 = cur + aoff;
    const unsigned char* B0 = cur + boff;

    // ---- phase 0: k-half 0, mi 0-1 ----
    i32x8 a0 = ldfrag(A0,         oh0);
    i32x8 a1 = ldfrag(A0 + 4096,  oh0);
    i32x8 b0 = ldfrag(B0,         oh0);
    i32x8 b1 = ldfrag(B0 + 4096,  oh0);
    PHASE_BAR();
    __builtin_amdgcn_s_setprio(1);
    acc[0][0] = MFMA_SC(a0, b0, acc[0][0]);
    acc[0][1] = MFMA_SC(a0, b1, acc[0][1]);
    acc[1][0] = MFMA_SC(a1, b0, acc[1][0]);
    acc[1][1] = MFMA_SC(a1, b1, acc[1][1]);
    __builtin_amdgcn_s_setprio(0);
    PHASE_BAR();

    // ---- phase 1: k-half 0, mi 2-3 (reuse b0,b1) ----
    i32x8 a2 = ldfrag(A0 + 8192,  oh0);
    i32x8 a3 = ldfrag(A0 + 12288, oh0);
    PHASE_BAR();
    __builtin_amdgcn_s_setprio(1);
    acc[2][0] = MFMA_SC(a2, b0, acc[2][0]);
    acc[2][1] = MFMA_SC(a2, b1, acc[2][1]);
    acc[3][0] = MFMA_SC(a3, b0, acc[3][0]);
    acc[3][1] = MFMA_SC(a3, b1, acc[3][1]);
    __builtin_amdgcn_s_setprio(0);
    PHASE_BAR();

    // ---- phase 2: k-half 1, mi 0-1 ----
    a0 = ldfrag(A0,         oh1);
    a1 = ldfrag(A0 + 4096,  oh1);
    b0 = ldfrag(B0,         oh1);
    b1 = ldfrag(B0 + 4096,  oh1);
    PHASE_BAR();
    __builtin_amdgcn_s_setprio(1);
    acc[0][0] = MFMA_SC(a0, b0, acc[0][0]);
    acc[0][1] = MFMA_SC(a0, b1, acc[0][1]);
    acc[1][0] = MFMA_SC(a1, b0, acc[1][0]);
    acc[1][1] = MFMA_SC(a1, b1, acc[1][1]);
    __builtin_amdgcn_s_setprio(0);
    PHASE_BAR();

    // ---- phase 3: k-half 1, mi 2-3 (reuse b0,b1) ----
    a2 = ldfrag(A0 + 8192,  oh1);
    a3 = ldfrag(A0 + 12288, oh1);
    PHASE_BAR();
    __builtin_amdgcn_s_setprio(1);
    acc[2][0] = MFMA_SC(a2, b0, acc[2][0]);
    acc[2][1] = MFMA_SC(a2, b1, acc[2][1]);
    acc[3][0] = MFMA_SC(a3, b0, acc[3][0]);
    acc[3][1] = MFMA_SC(a3, b1, acc[3][1]);
    __builtin_amdgcn_s_setprio(0);
    PHASE_BAR();

    unsigned char* tmp = cur; cur = nxt; nxt = tmp;
  }

  // Epilogue. C/D layout (32x32): col = lane&31, row = (reg&3)+8*(reg>>2)+4*(lane>>5).
  const int col = lane & 31, half = lane >> 5;
  float rn[2]; int sc[2]; bool sv[2];
  #pragma unroll
  for (int ni = 0; ni < 2; ++ni) {
    int s = s0 + wn * 64 + ni * 32 + col;
    sc[ni] = s;
    sv[ni] = (s < NP);
    rn[ni] = sv[ni] ? rnormS[s] : 0.f;
  }
  #pragma unroll
  for (int mi = 0; mi < 4; ++mi) {
    #pragma unroll
    for (int reg = 0; reg < 16; ++reg) {
      unsigned long long p = 0ull;
      #pragma unroll
      for (int ni = 0; ni < 2; ++ni) {
        float v = acc[mi][ni][reg] * rn[ni];
        unsigned long long cand =
            ((unsigned long long)ordf(v) << 32) |
            (unsigned long long)(0xFFFFFFFFu - (unsigned)sc[ni]);
        cand = sv[ni] ? cand : 0ull;
        if (cand > p) p = cand;
      }
      #pragma unroll
      for (int sh = 16; sh >= 1; sh >>= 1) {   // reduce within each 32-lane half
        unsigned long long o = __shfl_xor(p, sh, 64);
        if (o > p) p = o;
      }
      int q = q0 + wm * 128 + mi * 32 + (reg & 3) + 8 * (reg >> 2) + 4 * half;
      if (col == 0 && q < NP) atomicMax(best + q, p);
    }
  }
}

// ---------------------------------------------------------------------------
// 4) Final loss: loss = mean_q (synsq[q] - 2*dot + normsq[nn]) / 2304
// ---------------------------------------------------------------------------
__global__ void finalize_kernel(const unsigned long long* __restrict__ best,
                                const float* __restrict__ normS,
                                const float* __restrict__ normsqS,
                                const float* __restrict__ synsq,
                                float* __restrict__ out) {
  __shared__ float sm[256];
  int t = threadIdx.x;
  float accum = 0.f;
  for (int q = t; q < NP; q += 256) {
    unsigned long long p = best[q];
    unsigned int o   = (unsigned int)(p >> 32);
    unsigned int idx = 0xFFFFFFFFu - (unsigned int)(p & 0xFFFFFFFFull);
    unsigned int u   = (o & 0x80000000u) ? (o & 0x7FFFFFFFu) : ~o;
    float resp = __uint_as_float(u);
    float dot  = resp * normS[idx];
    accum += synsq[q] - 2.f * dot + normsqS[idx];
  }
  sm[t] = accum;
  __syncthreads();
  for (int s = 128; s >= 1; s >>= 1) {
    if (t < s) sm[t] += sm[t + s];
    __syncthreads();
  }
  if (t == 0) out[0] = sm[0] / ((float)NP * 2304.f);
}

// ---------------------------------------------------------------------------
extern "C" void kernel_launch(void* const* d_in, const int* in_sizes, int n_in,
                              void* d_out, int out_size, void* d_ws, size_t ws_size,
                              hipStream_t stream) {
  const float* inA = (const float*)d_in[0];  // input  (synthesis)
  const float* inB = (const float*)d_in[1];  // target (style)
  float* out = (float*)d_out;

  char* ws = (char*)d_ws;
  unsigned char* TA = (unsigned char*)ws;                 // 2,359,296 B fp8
  unsigned char* TB = (unsigned char*)(ws + 2359296);     // 2,359,296 B fp8
  float* rnormS  = (float*)(ws + 4718592);
  float* normS   = (float*)(ws + 4718592 + 35344);
  float* normsqS = (float*)(ws + 4718592 + 70688);
  float* synsq   = (float*)(ws + 4718592 + 106032);
  unsigned long long* best = (unsigned long long*)(ws + 4718592 + 141376);

  (void)hipMemsetAsync(best, 0, (size_t)NP * 8, stream);
  prep_kernel<<<dim3(1152), dim3(256), 0, stream>>>(inA, inB, (unsigned int*)TA, (unsigned int*)TB);
  norms_kernel<<<dim3((2 * NP + 3) / 4), dim3(256), 0, stream>>>(
      (const unsigned int*)TA, (const unsigned int*)TB, rnormS, normS, normsqS, synsq);
  gemm_argmax_kernel<<<dim3(NT2 * NT2), dim3(512), 0, stream>>>(TA, TB, rnormS, best);
  finalize_kernel<<<dim3(1), dim3(256), 0, stream>>>(best, normS, normsqS, synsq, out);
}

// Round 2
// 331.180 us; speedup vs baseline: 1.0614x; 1.0614x over previous
//
#include <hip/hip_runtime.h>
#include <math.h>

// Problem constants
#define NP 8836          // number of patches per image (94*94)
#define PW 94            // patches per row
#define IW 96            // image width/height
#define CH 256           // channels
#define NT2 35           // ceil(8836/256) output tiles per dim
#define KT2 18           // K steps: 2304/128 (BK=128 fp8 bytes)

typedef int   i32x4  __attribute__((ext_vector_type(4)));
typedef int   i32x8  __attribute__((ext_vector_type(8)));
typedef float f32x16 __attribute__((ext_vector_type(16)));

__device__ __forceinline__ unsigned int ordf(float f) {
  unsigned int u = __float_as_uint(f);
  return (u & 0x80000000u) ? ~u : (u | 0x80000000u);
}

typedef const __attribute__((address_space(1))) void GvoidC;
typedef __attribute__((address_space(3))) void Lvoid;
__device__ __forceinline__ void gl16(const void* g, void* l) {
  __builtin_amdgcn_global_load_lds((GvoidC*)g, (Lvoid*)l, 16, 0, 0);
}

// ---------------------------------------------------------------------------
// 1) Convert+transpose [C, 9216] fp32 -> [9216, C] fp8 (HW v_cvt encoding).
// ---------------------------------------------------------------------------
__global__ __launch_bounds__(256) void prep_kernel(
    const float* __restrict__ inA, const float* __restrict__ inB,
    unsigned int* __restrict__ TA, unsigned int* __restrict__ TB) {
  __shared__ float tile[64][65];
  int bid = blockIdx.x;            // [0, 1152)
  const float* src; unsigned int* dst;
  if (bid < 576) { src = inA; dst = TA; }
  else           { src = inB; dst = TB; bid -= 576; }
  int cT  = bid & 3;        // c-tile   [0,4)  (64 channels)
  int xyT = bid >> 2;       // xy-tile  [0,144)
  int t = threadIdx.x;
  int l = t & 63, h = t >> 6;

  #pragma unroll
  for (int i = 0; i < 16; ++i) {
    int c = h * 16 + i;
    tile[c][l] = src[(size_t)(cT * 64 + c) * (IW * IW) + xyT * 64 + l];
  }
  __syncthreads();
  int cu = t & 15;          // u32 column within the 64-channel tile
  #pragma unroll
  for (int i = 0; i < 4; ++i) {
    int xy = (t >> 4) + i * 16;
    int c = cu * 4;
    unsigned int v = __builtin_amdgcn_cvt_pk_fp8_f32(tile[c][xy],     tile[c + 1][xy], 0, false);
    v              = __builtin_amdgcn_cvt_pk_fp8_f32(tile[c + 2][xy], tile[c + 3][xy], v, true);
    dst[(size_t)(xyT * 64 + xy) * 64 + cT * 16 + cu] = v;
  }
}

// ---------------------------------------------------------------------------
// 2) Per-patch squared norms from the fp8 images (consistent with GEMM dtype).
// ---------------------------------------------------------------------------
__global__ void norms_kernel(const unsigned int* __restrict__ TA, const unsigned int* __restrict__ TB,
                             float* __restrict__ rnormS, float* __restrict__ normS,
                             float* __restrict__ normsqS, float* __restrict__ synsq) {
  int wid  = blockIdx.x * 4 + (threadIdx.x >> 6);
  int lane = threadIdx.x & 63;
  bool isStyle = wid < NP;
  int p = isStyle ? wid : wid - NP;
  if (p >= NP) return;
  const unsigned int* T = isStyle ? TB : TA;
  int pi = p / PW, pj = p % PW;
  float s = 0.f;
  #pragma unroll
  for (int kh = 0; kh < 3; ++kh) {
    #pragma unroll
    for (int kw = 0; kw < 3; ++kw) {
      unsigned int v = T[(size_t)((pi + kh) * IW + (pj + kw)) * 64 + lane];
      float f0 = __builtin_amdgcn_cvt_f32_fp8(v, 0);
      float f1 = __builtin_amdgcn_cvt_f32_fp8(v, 1);
      float f2 = __builtin_amdgcn_cvt_f32_fp8(v, 2);
      float f3 = __builtin_amdgcn_cvt_f32_fp8(v, 3);
      s += f0 * f0 + f1 * f1 + f2 * f2 + f3 * f3;
    }
  }
  #pragma unroll
  for (int m = 32; m >= 1; m >>= 1) s += __shfl_xor(s, m, 64);
  if (lane == 0) {
    if (isStyle) {
      normsqS[p] = s;
      float n = sqrtf(s);
      normS[p]  = n;
      rnormS[p] = 1.f / n;
    } else {
      synsq[p] = s;
    }
  }
}

// ---------------------------------------------------------------------------
// 3) MX-fp8 implicit-im2col GEMM+argmax, 256x256 tile, 8 waves (2Mx4N),
//    BK=128 bytes, double-buffered 128 KiB LDS.
//    K-loop structure (2 barriers, NO intra-step phase barriers):
//      barrier#1  : all waves finished reading nxt's old contents
//      issue 8 global_load_lds (tile kt+1) -> nxt
//      vmcnt(8)   : counted wait — tile kt's loads (issued last iter) done;
//                   the 8 new loads stay in flight across the barrier
//      barrier#2  : cur visibly filled for all waves
//      compute cur: 24 ds_read_b128 + 16 mfma_scale, straight-line, left to
//                   the compiler to interleave (fine-grained lgkmcnt) so the
//                   LDS pipe and matrix pipe overlap (max, not sum — the
//                   per-phase barrier variant serialized them: 336us, 24%).
//    Chunk-XOR LDS swizzle: logical 16B chunk q of row r lives at slot
//    q ^ (r&7); staging pre-swizzles the GLOBAL source chunk so the LDS dest
//    stays linear (global_load_lds requirement), reads apply the same XOR.
// ---------------------------------------------------------------------------
__device__ __forceinline__ i32x8 ldfrag(const unsigned char* rowp, int o0) {
  i32x4 lo = *(const i32x4*)(rowp + o0);
  i32x4 hi = *(const i32x4*)(rowp + (o0 ^ 16));   // (c0+1)^sw = (c0^sw)^1
  return __builtin_shufflevector(lo, hi, 0, 1, 2, 3, 4, 5, 6, 7);
}

#define MFMA_SC(AF, BF, ACC) \
  __builtin_amdgcn_mfma_scale_f32_32x32x64_f8f6f4(AF, BF, ACC, \
      0, 0,              /* A fmt = fp8(e4m3), B fmt = fp8 */  \
      0, 0x7F7F7F7F,     /* opsel_a, scale_a = 1.0 */          \
      0, 0x7F7F7F7F)     /* opsel_b, scale_b = 1.0 */

__global__ __launch_bounds__(512, 2) void gemm_argmax_kernel(
    const unsigned char* __restrict__ TA, const unsigned char* __restrict__ TB,
    const float* __restrict__ rnormS, unsigned long long* __restrict__ best) {
  // [2 buffers][A 32KB | B 32KB]
  __shared__ unsigned char lds[131072];

  const int pid = blockIdx.x;
  const int mt = pid % NT2, nt = pid / NT2;
  const int q0 = mt * 256, s0 = nt * 256;
  const int t = threadIdx.x, lane = t & 63, wave = t >> 6;
  const int wm = wave >> 2, wn = wave & 3;        // 2 x 4 wave grid

  // Staging: instr i of thread t writes LDS offset i*8192 + t*16,
  // i.e. row 64*i + (t>>3), slot t&7. Fetch global chunk qc = (t&7)^(row&7).
  const int rr = t >> 3;
  const int qc = (t & 7) ^ (rr & 7);
  const unsigned char* gA[4];
  const unsigned char* gB[4];
  #pragma unroll
  for (int i = 0; i < 4; ++i) {
    int qa = q0 + 64 * i + rr; if (qa > NP - 1) qa = NP - 1;
    int sa = s0 + 64 * i + rr; if (sa > NP - 1) sa = NP - 1;
    gA[i] = TA + (size_t)((qa / PW) * IW + (qa % PW)) * CH + qc * 16;
    gB[i] = TB + (size_t)((sa / PW) * IW + (sa % PW)) * CH + qc * 16;
  }
  const int t16 = t * 16;

  f32x16 acc[4][2];
  #pragma unroll
  for (int mi = 0; mi < 4; ++mi)
    #pragma unroll
    for (int ni = 0; ni < 2; ++ni)
      #pragma unroll
      for (int j = 0; j < 16; ++j) acc[mi][ni][j] = 0.f;

  // Fragment reads: A row = wm*128 + mi*32 + (lane&31), B row = wn*64 +
  // ni*32 + (lane&31), row stride 128 B. k-half h: logical chunks
  // c0 = 2*(lane>>5) + 4h, c0+1; slot = c ^ (lane&7).
  const int kq = lane >> 5, sw = lane & 7;
  const int oh0 = ((2 * kq)     ^ sw) * 16;
  const int oh1 = ((2 * kq + 4) ^ sw) * 16;
  const int aoff = (wm * 128 + (lane & 31)) * 128;
  const int boff = 32768 + (wn * 64 + (lane & 31)) * 128;

  unsigned char* cur = lds;
  unsigned char* nxt = lds + 65536;

  // Prologue: stage tile 0 (choff = 0).
  #pragma unroll
  for (int i = 0; i < 4; ++i) {
    gl16(gA[i], cur + i * 8192 + t16);
    gl16(gB[i], cur + 32768 + i * 8192 + t16);
  }

  #pragma unroll 1
  for (int kt = 0; kt < KT2; ++kt) {
    // barrier#1: every wave has finished its LDS reads of nxt's previous
    // contents (reads are consumed by MFMAs that precede this point in
    // program order) — safe to let new DMA writes land in nxt.
    __builtin_amdgcn_s_barrier();
    asm volatile("" ::: "memory");

    if (kt + 1 < KT2) {
      int c = (kt + 1) >> 1;                       // which (kh,kw) of 9
      int kh = c / 3, kw = c - kh * 3;
      int choff = (kh * IW + kw) * CH + ((kt + 1) & 1) * 128;
      #pragma unroll
      for (int i = 0; i < 4; ++i) {
        gl16(gA[i] + choff, nxt + i * 8192 + t16);
        gl16(gB[i] + choff, nxt + 32768 + i * 8192 + t16);
      }
      // Counted wait: tile kt's 8 loads (issued a full K-step ago) are done;
      // the 8 newest (tile kt+1) remain in flight across the barrier.
      asm volatile("s_waitcnt vmcnt(8)" ::: "memory");
    } else {
      asm volatile("s_waitcnt vmcnt(0)" ::: "memory");
    }
    // barrier#2: cur is filled and visible to all waves.
    __builtin_amdgcn_s_barrier();
    asm volatile("" ::: "memory");

    const unsigned char* A0 = cur + aoff;
    const unsigned char* B0 = cur + boff;

    // Straight-line compute: compiler interleaves ds_read_b128 with MFMA
    // (fine-grained lgkmcnt), overlapping LDS and matrix pipes.
    #pragma unroll
    for (int h = 0; h < 2; ++h) {
      const int oh = h ? oh1 : oh0;
      i32x8 b0 = ldfrag(B0,         oh);
      i32x8 b1 = ldfrag(B0 + 4096,  oh);
      i32x8 a0 = ldfrag(A0,         oh);
      i32x8 a1 = ldfrag(A0 + 4096,  oh);
      i32x8 a2 = ldfrag(A0 + 8192,  oh);
      i32x8 a3 = ldfrag(A0 + 12288, oh);
      acc[0][0] = MFMA_SC(a0, b0, acc[0][0]);
      acc[0][1] = MFMA_SC(a0, b1, acc[0][1]);
      acc[1][0] = MFMA_SC(a1, b0, acc[1][0]);
      acc[1][1] = MFMA_SC(a1, b1, acc[1][1]);
      acc[2][0] = MFMA_SC(a2, b0, acc[2][0]);
      acc[2][1] = MFMA_SC(a2, b1, acc[2][1]);
      acc[3][0] = MFMA_SC(a3, b0, acc[3][0]);
      acc[3][1] = MFMA_SC(a3, b1, acc[3][1]);
    }

    unsigned char* tmp = cur; cur = nxt; nxt = tmp;
  }

  // Epilogue. C/D layout (32x32): col = lane&31, row = (reg&3)+8*(reg>>2)+4*(lane>>5).
  const int col = lane & 31, half = lane >> 5;
  float rn[2]; int sc[2]; bool sv[2];
  #pragma unroll
  for (int ni = 0; ni < 2; ++ni) {
    int s = s0 + wn * 64 + ni * 32 + col;
    sc[ni] = s;
    sv[ni] = (s < NP);
    rn[ni] = sv[ni] ? rnormS[s] : 0.f;
  }
  #pragma unroll
  for (int mi = 0; mi < 4; ++mi) {
    #pragma unroll
    for (int reg = 0; reg < 16; ++reg) {
      unsigned long long p = 0ull;
      #pragma unroll
      for (int ni = 0; ni < 2; ++ni) {
        float v = acc[mi][ni][reg] * rn[ni];
        unsigned long long cand =
            ((unsigned long long)ordf(v) << 32) |
            (unsigned long long)(0xFFFFFFFFu - (unsigned)sc[ni]);
        cand = sv[ni] ? cand : 0ull;
        if (cand > p) p = cand;
      }
      #pragma unroll
      for (int sh = 16; sh >= 1; sh >>= 1) {   // reduce within each 32-lane half
        unsigned long long o = __shfl_xor(p, sh, 64);
        if (o > p) p = o;
      }
      int q = q0 + wm * 128 + mi * 32 + (reg & 3) + 8 * (reg >> 2) + 4 * half;
      if (col == 0 && q < NP) atomicMax(best + q, p);
    }
  }
}

// ---------------------------------------------------------------------------
// 4) Final loss: loss = mean_q (synsq[q] - 2*dot + normsq[nn]) / 2304
// ---------------------------------------------------------------------------
__global__ void finalize_kernel(const unsigned long long* __restrict__ best,
                                const float* __restrict__ normS,
                                const float* __restrict__ normsqS,
                                const float* __restrict__ synsq,
                                float* __restrict__ out) {
  __shared__ float sm[256];
  int t = threadIdx.x;
  float accum = 0.f;
  for (int q = t; q < NP; q += 256) {
    unsigned long long p = best[q];
    unsigned int o   = (unsigned int)(p >> 32);
    unsigned int idx = 0xFFFFFFFFu - (unsigned int)(p & 0xFFFFFFFFull);
    unsigned int u   = (o & 0x80000000u) ? (o & 0x7FFFFFFFu) : ~o;
    float resp = __uint_as_float(u);
    float dot  = resp * normS[idx];
    accum += synsq[q] - 2.f * dot + normsqS[idx];
  }
  sm[t] = accum;
  __syncthreads();
  for (int s = 128; s >= 1; s >>= 1) {
    if (t < s) sm[t] += sm[t + s];
    __syncthreads();
  }
  if (t == 0) out[0] = sm[0] / ((float)NP * 2304.f);
}

// ---------------------------------------------------------------------------
extern "C" void kernel_launch(void* const* d_in, const int* in_sizes, int n_in,
                              void* d_out, int out_size, void* d_ws, size_t ws_size,
                              hipStream_t stream) {
  const float* inA = (const float*)d_in[0];  // input  (synthesis)
  const float* inB = (const float*)d_in[1];  // target (style)
  float* out = (float*)d_out;

  char* ws = (char*)d_ws;
  unsigned char* TA = (unsigned char*)ws;                 // 2,359,296 B fp8
  unsigned char* TB = (unsigned char*)(ws + 2359296);     // 2,359,296 B fp8
  float* rnormS  = (float*)(ws + 4718592);
  float* normS   = (float*)(ws + 4718592 + 35344);
  float* normsqS = (float*)(ws + 4718592 + 70688);
  float* synsq   = (float*)(ws + 4718592 + 106032);
  unsigned long long* best = (unsigned long long*)(ws + 4718592 + 141376);

  (void)hipMemsetAsync(best, 0, (size_t)NP * 8, stream);
  prep_kernel<<<dim3(1152), dim3(256), 0, stream>>>(inA, inB, (unsigned int*)TA, (unsigned int*)TB);
  norms_kernel<<<dim3((2 * NP + 3) / 4), dim3(256), 0, stream>>>(
      (const unsigned int*)TA, (const unsigned int*)TB, rnormS, normS, normsqS, synsq);
  gemm_argmax_kernel<<<dim3(NT2 * NT2), dim3(512), 0, stream>>>(TA, TB, rnormS, best);
  finalize_kernel<<<dim3(1), dim3(256), 0, stream>>>(best, normS, normsqS, synsq, out);
}